// Round 8
// baseline (340.872 us; speedup 1.0000x reference)
//
#include <hip/hip_runtime.h>
#include <stdint.h>

#define N_TOK 2048
#define DDIM 1024
#define HDIM 4096
#define NEXP 8
#define MAXT64 40              // max 64-row tiles: worst case 32+7 = 39

// ctrl block layout (int offsets into d_ws)
#define C_COUNTS 0
#define C_CURSOR 8
#define C_PADOFF 16
#define C_TILECNT 24
#define C_TILE_E 32            // 48 slots
#define C_TILE_M0 80           // 48 slots
#define C_TILE_ROWS 128        // 48 slots
#define C_EXPERT 192           // 2048
#define C_PERM 2304            // 2560 slots

// workspace layout (bf16 weights path; verified in use by R7 bench)
#define ACAPB 2304
#define XGB_OFF 32768
#define HGB_OFF (XGB_OFF + ACAPB*DDIM*2)
#define W1B_OFF (HGB_OFF + ACAPB*HDIM*2)
#define W2B_OFF (W1B_OFF + (size_t)NEXP*DDIM*HDIM*2)

typedef float f32x4 __attribute__((ext_vector_type(4)));
typedef short s16x8 __attribute__((ext_vector_type(8)));
typedef unsigned int u32;
typedef u32 u32x2 __attribute__((ext_vector_type(2)));
typedef unsigned short u16;

__device__ __forceinline__ u16 f2bf(float f){
  u32 u = __float_as_uint(f);
  u += 0x7fffu + ((u >> 16) & 1u);   // RNE
  return (u16)(u >> 16);
}

__device__ __forceinline__ u32 pkbf(float a, float b){   // {lo16=bf(a), hi16=bf(b)}
  u32 r; asm("v_cvt_pk_bf16_f32 %0, %1, %2" : "=v"(r) : "v"(a), "v"(b)); return r;
}

// ---------------- gating: fp32 logits, argmax (first-max tie rule), counts ---
__global__ __launch_bounds__(256) void gate_kern(
    const float* __restrict__ x, const float* __restrict__ gw,
    const float* __restrict__ gb, int* __restrict__ ctrl)
{
  const int wv = threadIdx.x >> 6, l = threadIdx.x & 63;
  const int n = blockIdx.x * 4 + wv;            // one wave per token
  const float* xr = x + (size_t)n * DDIM;
  float acc[NEXP];
  #pragma unroll
  for (int e = 0; e < NEXP; e++) acc[e] = 0.f;
  #pragma unroll 4
  for (int i = 0; i < DDIM/64; i++){
    int k = i*64 + l;
    float xv = xr[k];
    const float* g = gw + (size_t)k * NEXP;
    #pragma unroll
    for (int e = 0; e < NEXP; e++) acc[e] = fmaf(xv, g[e], acc[e]);
  }
  #pragma unroll
  for (int e = 0; e < NEXP; e++){
    #pragma unroll
    for (int off = 32; off > 0; off >>= 1) acc[e] += __shfl_xor(acc[e], off);
  }
  if (l == 0){
    float best = acc[0] + gb[0]; int bi = 0;
    #pragma unroll
    for (int e = 1; e < NEXP; e++){
      float v = acc[e] + gb[e];
      if (v > best){ best = v; bi = e; }        // strict > keeps first index
    }
    ctrl[C_EXPERT + n] = bi;
    atomicAdd(&ctrl[C_COUNTS + bi], 1);
  }
}

// ------------- setup: aux loss, offsets (tight pack), 64-row tile table ------
__global__ void setup_kern(int* __restrict__ ctrl, float* __restrict__ aux_out)
{
  const int t = threadIdx.x;
  for (int i = t; i < 2560; i += 256) ctrl[C_PERM + i] = -1;
  if (t == 0){
    int off = 0, tc = 0;
    float aux = 0.f;
    for (int e = 0; e < NEXP; e++){
      int c = ctrl[C_COUNTS + e];
      ctrl[C_PADOFF + e] = off;
      ctrl[C_CURSOR + e] = off;
      int nt = (c + 63) / 64;
      for (int j = 0; j < nt; j++){
        ctrl[C_TILE_E   + tc] = e;
        ctrl[C_TILE_M0  + tc] = off + j*64;
        ctrl[C_TILE_ROWS+ tc] = min(64, c - j*64);
        tc++;
      }
      off += c;                                  // tight packing, no padding
      float fr = (float)c * (1.f/(float)N_TOK);
      float d = fr - 1.f/(float)NEXP;
      aux += d*d;
    }
    ctrl[C_TILECNT] = tc;
    *aux_out = aux * (1.f/(float)NEXP);
  }
}

// ------------------------- scatter tokens into grouped slots -----------------
__global__ __launch_bounds__(256) void scatter_kern(int* __restrict__ ctrl)
{
  const int n = blockIdx.x * 256 + threadIdx.x;
  const int e = ctrl[C_EXPERT + n];
  const int pos = atomicAdd(&ctrl[C_CURSOR + e], 1);
  ctrl[C_PERM + pos] = n;
}

// ------------------ gather + f32->bf16 convert of x into Xg ------------------
__global__ __launch_bounds__(256) void xg_kern(
    const float* __restrict__ x, const int* __restrict__ ctrl,
    u16* __restrict__ Xg)
{
  const int slot = blockIdx.x, t = threadIdx.x;
  const int tok = ctrl[C_PERM + slot];
  ushort4 o;
  if (tok >= 0){
    f32x4 v = *(const f32x4*)(x + (size_t)tok*DDIM + t*4);
    o.x = f2bf(v.x); o.y = f2bf(v.y); o.z = f2bf(v.z); o.w = f2bf(v.w);
  } else { o.x = 0; o.y = 0; o.z = 0; o.w = 0; }
  *(ushort4*)(Xg + (size_t)slot*DDIM + t*4) = o;
}

// ---------------- W transpose-convert: [E][K][NN] f32 -> [E][NN][K] bf16 -----
// Measured ~4.2 TB/s in R7 (the control experiment that isolated the GEMM cap).
__global__ __launch_bounds__(256) void wconv_kern(
    const float* __restrict__ src, u16* __restrict__ dst, int K, int NN)
{
  const int TN = NN >> 6, TK = K >> 6;
  int b = blockIdx.x;
  const int e  = b / (TK*TN); b -= e*TK*TN;
  const int kt = b / TN;
  const int nt = b - kt*TN;
  const int t = threadIdx.x;

  __shared__ float ld[64][67];

  const float* S = src + (size_t)e*K*NN + (size_t)(kt*64)*NN + nt*64;
  #pragma unroll
  for (int p = 0; p < 4; p++){
    int kr = p*16 + (t >> 4);
    int nc = (t & 15) * 4;
    f32x4 v = *(const f32x4*)(S + (size_t)kr*NN + nc);
    ld[kr][nc+0] = v.x; ld[kr][nc+1] = v.y; ld[kr][nc+2] = v.z; ld[kr][nc+3] = v.w;
  }
  __syncthreads();

  u16* D = dst + (size_t)e*NN*K + (size_t)(nt*64)*K + kt*64;
  #pragma unroll
  for (int q = 0; q < 2; q++){
    int s = q*256 + t;
    int n = s >> 3, kc = s & 7;
    union { u32 u[4]; } o;
    #pragma unroll
    for (int j = 0; j < 4; j++)
      o.u[j] = pkbf(ld[kc*8 + 2*j][n], ld[kc*8 + 2*j + 1][n]);
    *(u32x2*)(D + (size_t)n*K + kc*8)     = (u32x2){o.u[0], o.u[1]};
    *(u32x2*)(D + (size_t)n*K + kc*8 + 4) = (u32x2){o.u[2], o.u[3]};
  }
}

// ----------------- wave-independent GEMMs (no LDS, no barriers) --------------
// MODE 1: Hg = gelu(Xg @ W1b' + b1)   K=1024, NN=4096
// MODE 2: out[tok] += Hg @ W2b' + b2  K=4096, NN=1024, split-K x4 + atomics
//
// One 64x64 output tile per WAVE; both operands' MFMA fragments are
// 16B-contiguous per lane (bf16 K-major), loaded fragment-direct as
// global_load_dwordx4 (full 64B lines; fixes R4's 16x strided overfetch).
// Register double-buffer keeps ~8KB/wave permanently in flight; there is no
// vmcnt(0) drain anywhere in the loop -> HBM/L2 queues never empty (the
// measured invariant killing every barrier-synced variant, R0-R7).
// Tile order: consecutive waves share a W-panel; XCD-chunk swizzle pins each
// panel to one XCD's L2.
template<int MODE>
__global__ __launch_bounds__(256, 2) void moe_gemm_wv(
    const u16* __restrict__ Ag, const u16* __restrict__ Wt,
    const float* __restrict__ bias, u16* __restrict__ Hg,
    float* __restrict__ outp, const int* __restrict__ ctrl)
{
  constexpr int K    = (MODE==1) ? DDIM : HDIM;
  constexpr int NN   = (MODE==1) ? HDIM : DDIM;
  constexpr int KS   = (MODE==1) ? 1 : 4;
  constexpr int KLOC = K / KS;                 // 1024 / 1024
  constexpr int NST  = KLOC / 32;              // 32 K-steps

  // XCD-chunk swizzle (grid 640, 640%8==0 -> simple bijective form)
  const int cpx = gridDim.x >> 3;
  const int bsw = (blockIdx.x & 7) * cpx + (blockIdx.x >> 3);
  const int tid = threadIdx.x;
  const int wwid = bsw*4 + (tid >> 6);

  const int mt  = wwid % MAXT64;
  const int nks = wwid / MAXT64;
  if (mt >= ctrl[C_TILECNT]) return;
  const int nt = (KS==1) ? nks : (nks >> 2);
  const int ks = (KS==1) ? 0   : (nks & 3);

  const int e    = ctrl[C_TILE_E + mt];
  const int m0   = ctrl[C_TILE_M0 + mt];
  const int rows = ctrl[C_TILE_ROWS + mt];
  const int n0   = nt * 64;
  const int kb   = ks * KLOC;

  const int l = tid & 63;
  const int lhi = l >> 4, llo = l & 15;

  f32x4 acc[4][4];
  #pragma unroll
  for (int mf = 0; mf < 4; mf++)
    #pragma unroll
    for (int nf = 0; nf < 4; nf++) acc[mf][nf] = (f32x4){0.f,0.f,0.f,0.f};

  const u16* Ap = Ag + (size_t)(m0 + llo)*K + lhi*8 + kb;
  const u16* Bp = Wt + (size_t)e*NN*K + (size_t)(n0 + llo)*K + lhi*8 + kb;

  s16x8 a0[4], b0[4], a1[4], b1[4];

#define LOADF(AF, BF, ko) { \
    _Pragma("unroll") \
    for (int mf = 0; mf < 4; mf++) AF[mf] = *(const s16x8*)(Ap + (size_t)mf*16*K + (ko)); \
    _Pragma("unroll") \
    for (int nf = 0; nf < 4; nf++) BF[nf] = *(const s16x8*)(Bp + (size_t)nf*16*K + (ko)); }

#define MF16(AF, BF) { \
    _Pragma("unroll") \
    for (int mf = 0; mf < 4; mf++) \
      _Pragma("unroll") \
      for (int nf = 0; nf < 4; nf++) \
        acc[mf][nf] = __builtin_amdgcn_mfma_f32_16x16x32_bf16(AF[mf], BF[nf], acc[mf][nf], 0, 0, 0); }

  LOADF(a0, b0, 0);
  #pragma unroll 1
  for (int t = 0; t < NST; t += 2){
    if (t+1 < NST){ LOADF(a1, b1, (t+1)*32); }
    MF16(a0, b0);
    if (t+2 < NST){ LOADF(a0, b0, (t+2)*32); }
    if (t+1 < NST){ MF16(a1, b1); }
  }

  if constexpr (MODE == 1){
    const float* bp = bias + (size_t)e*NN + n0;
    #pragma unroll
    for (int nf = 0; nf < 4; nf++){
      const int cl = nf*16 + llo;
      const float bb = bp[cl];
      #pragma unroll
      for (int mf = 0; mf < 4; mf++){
        #pragma unroll
        for (int r = 0; r < 4; r++){
          const int rl = mf*16 + lhi*4 + r;
          if (rl < rows){
            float vv = acc[mf][nf][r] + bb;
            float gel = 0.5f * vv * (1.0f + erff(vv * 0.70710678118f)); // exact gelu
            Hg[(size_t)(m0+rl)*NN + n0 + cl] = f2bf(gel);
          }
        }
      }
    }
  } else {
    const float* bp = bias + (size_t)e*NN + n0;
    const bool addb = (ks == 0);
    #pragma unroll
    for (int mf = 0; mf < 4; mf++){
      #pragma unroll
      for (int r = 0; r < 4; r++){
        const int rl = mf*16 + lhi*4 + r;
        if (rl < rows){
          const int tok = ctrl[C_PERM + m0 + rl];
          #pragma unroll
          for (int nf = 0; nf < 4; nf++){
            const int cl = nf*16 + llo;
            float v = acc[mf][nf][r] + (addb ? bp[cl] : 0.f);
            atomicAdd(&outp[(size_t)tok*DDIM + n0 + cl], v);
          }
        }
      }
    }
  }
#undef LOADF
#undef MF16
}

extern "C" void kernel_launch(void* const* d_in, const int* in_sizes, int n_in,
                              void* d_out, int out_size, void* d_ws, size_t ws_size,
                              hipStream_t stream)
{
  (void)in_sizes; (void)n_in; (void)out_size; (void)ws_size;
  const float* x  = (const float*)d_in[0];
  const float* gw = (const float*)d_in[1];
  const float* gb = (const float*)d_in[2];
  const float* w1 = (const float*)d_in[3];
  const float* b1 = (const float*)d_in[4];
  const float* w2 = (const float*)d_in[5];
  const float* b2 = (const float*)d_in[6];
  float* out = (float*)d_out;
  char* ws = (char*)d_ws;
  int* ctrl = (int*)ws;
  u16* Xg  = (u16*)(ws + XGB_OFF);
  u16* Hg  = (u16*)(ws + HGB_OFF);
  u16* W1b = (u16*)(ws + W1B_OFF);
  u16* W2b = (u16*)(ws + W2B_OFF);

  // grid for both GEMMs: MAXT64 * (NN/64) * KS / 4 waves-per-block = 640 blocks
  const int GEMM_BLOCKS = MAXT64 * 64 / 4;      // MODE1: 40*64*1/4 = 640
  // MODE2: 40*16*4/4 = 640 as well

  hipMemsetAsync(ctrl, 0, 64, stream);                       // counts
  hipMemsetAsync(out, 0, (size_t)N_TOK*DDIM*4, stream);      // split-K accum base
  gate_kern<<<N_TOK/4, 256, 0, stream>>>(x, gw, gb, ctrl);
  setup_kern<<<1, 256, 0, stream>>>(ctrl, out + (size_t)N_TOK*DDIM);
  scatter_kern<<<N_TOK/256, 256, 0, stream>>>(ctrl);
  xg_kern<<<N_TOK, 256, 0, stream>>>(x, ctrl, Xg);

  // interleave conversion and consumption so each W is L3-hot for its GEMM
  wconv_kern<<<NEXP*(DDIM/64)*(HDIM/64), 256, 0, stream>>>(w1, W1b, DDIM, HDIM);
  moe_gemm_wv<1><<<GEMM_BLOCKS, 256, 0, stream>>>(Xg, W1b, b1, Hg, nullptr, ctrl);
  wconv_kern<<<NEXP*(HDIM/64)*(DDIM/64), 256, 0, stream>>>(w2, W2b, HDIM, DDIM);
  moe_gemm_wv<2><<<GEMM_BLOCKS, 256, 0, stream>>>(Hg, W2b, b2, nullptr, out, ctrl);
}